// Round 1
// baseline (285.205 us; speedup 1.0000x reference)
//
#include <hip/hip_runtime.h>

// SparseDIA (9 static offsets) @ dense: out[r,c] = sum_k diags[k, r+off_k] * other[r+off_k, c]
// N=8192, M=4096 fp32. HBM traffic is already compulsory (~270 MB); the bottleneck is the
// 9x cache-side read amplification (1.2 GB through L1/L2). Fix: register row-tiling.
// Each block computes TR=16 consecutive rows x 256 float4 columns. The near-offset
// cluster {-8,-1,0,1,8} shares one 32-row window (each input row loaded ONCE and
// scattered into up to 5 accumulators); far offsets (+-64,+-128) load 16 rows each.
// 96 loads / 16 rows vs 144 -> amplification 9 -> 6.

#define DIA_N 8192
#define DIA_M 4096
#define M4 (DIA_M / 4)   // float4 columns per row = 1024
#define TR 16            // output rows per block/thread

typedef float f4 __attribute__((ext_vector_type(4)));

__global__ __launch_bounds__(256, 4) void sparse_dia_kernel(
    const float* __restrict__ diags,   // [9, N]
    const float* __restrict__ other,   // [N, M]
    float* __restrict__ out)           // [N, M]
{
    const int r0 = blockIdx.y * TR;                       // first output row of this block
    const int c4 = blockIdx.x * 256 + threadIdx.x;        // float4 column index

    const f4* __restrict__ o4 = (const f4*)other;
    f4* __restrict__ out4     = (f4*)out;

    f4 acc[TR];
#pragma unroll
    for (int i = 0; i < TR; ++i) acc[i] = (f4){0.f, 0.f, 0.f, 0.f};

    if (r0 >= 128 && r0 + TR + 128 <= DIA_N) {
        // ---- Interior fast path: all offsets in range, no guards ----

        // Far offsets: no row overlap at TR=16, one load per (offset,row).
        constexpr int FOFF[4] = {-128, -64, 64, 128};
        constexpr int FK[4]   = {0, 1, 7, 8};
#pragma unroll
        for (int f = 0; f < 4; ++f) {
            const int off = FOFF[f];
            const int k   = FK[f];
#pragma unroll
            for (int i = 0; i < TR; ++i) {
                const int q   = r0 + i + off;
                const float d = diags[k * DIA_N + q];     // block-uniform -> scalar load
                const f4 v    = o4[q * M4 + c4];
                acc[i] += d * v;
            }
        }

        // Near cluster: offsets {-8,-1,0,1,8} (k = 2..6). Input rows
        // [r0-8, r0+TR+8) each loaded ONCE, scattered to up to 5 accumulators.
        // out[i] += diags[k, q] * other[q] with q = r0+j, i = j - off.
#pragma unroll
        for (int j = -8; j < TR + 8; ++j) {
            const int q = r0 + j;
            const f4 v  = o4[q * M4 + c4];
            if (j + 8 >= 0 && j + 8 < TR) acc[j + 8] += diags[2 * DIA_N + q] * v;  // off=-8
            if (j + 1 >= 0 && j + 1 < TR) acc[j + 1] += diags[3 * DIA_N + q] * v;  // off=-1
            if (j     >= 0 && j     < TR) acc[j    ] += diags[4 * DIA_N + q] * v;  // off= 0
            if (j - 1 >= 0 && j - 1 < TR) acc[j - 1] += diags[5 * DIA_N + q] * v;  // off=+1
            if (j - 8 >= 0 && j - 8 < TR) acc[j - 8] += diags[6 * DIA_N + q] * v;  // off=+8
        }
    } else {
        // ---- Edge path (first/last ~128 rows): guard every access. ----
        // Branches are block-uniform in practice (q depends only on r0 + consts).
        constexpr int OFF[9] = {-128, -64, -8, -1, 0, 1, 8, 64, 128};
#pragma unroll
        for (int k = 0; k < 9; ++k) {
#pragma unroll
            for (int i = 0; i < TR; ++i) {
                const int q = r0 + i + OFF[k];
                if (q >= 0 && q < DIA_N) {
                    const float d = diags[k * DIA_N + q];
                    const f4 v    = o4[q * M4 + c4];
                    acc[i] += d * v;
                }
            }
        }
    }

    // out is never re-read in this dispatch: nontemporal store reduces L3
    // pollution so `other` stays cache-resident.
#pragma unroll
    for (int i = 0; i < TR; ++i) {
        __builtin_nontemporal_store(acc[i], &out4[(r0 + i) * M4 + c4]);
    }
}

extern "C" void kernel_launch(void* const* d_in, const int* in_sizes, int n_in,
                              void* d_out, int out_size, void* d_ws, size_t ws_size,
                              hipStream_t stream) {
    const float* diags = (const float*)d_in[0];   // 9 * 8192 fp32
    const float* other = (const float*)d_in[1];   // 8192 * 4096 fp32
    float* out         = (float*)d_out;           // 8192 * 4096 fp32

    // 256 threads = 256 float4 columns; grid.x = M4/256 = 4; grid.y = N/TR = 512.
    dim3 block(256, 1, 1);
    dim3 grid(M4 / 256, DIA_N / TR, 1);
    sparse_dia_kernel<<<grid, block, 0, stream>>>(diags, other, out);
}

// Round 2
// 260.752 us; speedup vs baseline: 1.0938x; 1.0938x over previous
//
#include <hip/hip_runtime.h>

// SparseDIA (9 static offsets) @ dense: out[r,c] = sum_k diags[k, r+off_k] * other[r+off_k, c]
// N=8192, M=4096 fp32.
//
// Round-1 findings: (a) compulsory HBM traffic needs the reuse window XCD-local and
// temporally tight; (b) the binding limit is the aggregate vector-memory path
// (~12 TB/s observed), not HBM BW. So: stage input rows in LDS to cut the 9x read
// amplification to 2x, via global_load_lds (no VGPR roundtrip), with a grid whose
// XCD mapping (blockIdx.x % 8) pins each column stripe + its row-overlap reuse to
// one XCD's L2.
//
// Block geometry: 256 output rows x 8 float4 cols (128 B wide). Staged window =
// 512 rows x 128 B = 64 KB LDS + 9 KB zero-padded diag slice (edge handling is
// free: OOB rows clamp, their diag is staged as 0). 256 threads = 8 cols x 32
// row-tiles of 8 rows. Compute is pure LDS: per output f4, 9 ds_read_b128
// (8 distinct 16B slots x 8 rows per wave = minimal bank occupancy) + 9 broadcast
// ds_read_b32. 2 blocks/CU (146 KB LDS); latency hidden by the 16-deep async
// staging queue per wave, not wave count.

#define DIA_N 8192
#define DIA_M 4096
#define M4   (DIA_M / 4)   // float4 per row = 1024
#define CB   8             // float4 columns per block
#define BR   256           // output rows per block
#define HALO 128           // max |offset|
#define WIN  (BR + 2*HALO) // staged rows = 512
#define TR   8             // output rows per thread

typedef float f4 __attribute__((ext_vector_type(4)));

typedef __attribute__((address_space(3))) unsigned int       lds_uint;
typedef const __attribute__((address_space(1))) unsigned int glb_uint;

__global__ __launch_bounds__(256) void sparse_dia_kernel(
    const float* __restrict__ diags,   // [9, N]
    const float* __restrict__ other,   // [N, M]
    float* __restrict__ out)           // [N, M]
{
    constexpr int OFF[9] = {-128, -64, -8, -1, 0, 1, 8, 64, 128};

    __shared__ f4    olds[WIN][CB];      // 512 * 128 B = 64 KB, linear (global_load_lds dest)
    __shared__ float dlds[9 * BR];       // diag slice, output-row-indexed, zero-padded: 9 KB

    const int tid  = threadIdx.x;
    const int r0   = blockIdx.y * BR;          // first output row
    const int cb4  = blockIdx.x * CB;          // first float4 column

    // ---- Stage diags: dlds[k][i] = diags[k, r0+i+OFF[k]] or 0 if out of range ----
    // (this zero-padding is the entire edge-handling strategy)
#pragma unroll
    for (int f = tid; f < 9 * BR; f += 256) {
        const int k = f >> 8;          // BR = 256
        const int i = f & (BR - 1);
        const int q = r0 + i + OFF[k];
        dlds[f] = (q >= 0 && q < DIA_N) ? diags[k * DIA_N + q] : 0.f;
    }

    // ---- Stage other rows [r0-HALO, r0+BR+HALO) x 8 f4 cols into LDS ----
    // 64 wave-instructions of 1 KB each (8 rows x 128 B), 16 per wave.
    // LDS dest is wave-uniform base + lane*16 (linear); global src is per-lane.
    {
        const int wave = tid >> 6;
        const int lane = tid & 63;
        const int lrow = lane >> 3;            // 0..7 row within chunk
        const int lcol = lane & 7;             // 0..7 f4 col
#pragma unroll
        for (int s = 0; s < 16; ++s) {
            const int chunk = wave * 16 + s;   // 0..63, covers 8 rows
            int q = r0 - HALO + chunk * 8 + lrow;
            q = (q < 0) ? 0 : (q >= DIA_N ? DIA_N - 1 : q);   // clamp; diag=0 kills garbage
            const float* src = other + ((size_t)q * DIA_M + (size_t)(cb4 + lcol) * 4);
            __builtin_amdgcn_global_load_lds(
                (glb_uint*)src,
                (lds_uint*)&olds[chunk * 8][0],   // wave-uniform base
                16, 0, 0);
        }
    }

    __syncthreads();   // drains vmcnt + lgkmcnt

    // ---- Compute: each thread = 1 f4 column x 8 consecutive rows ----
    const int c  = tid & 7;        // f4 col (wave: 8 cols x 8 row-tiles -> minimal bank load)
    const int rt = tid >> 3;       // 0..31 row tile

    const f4* __restrict__ ow = (const f4*)other; (void)ow;
    f4* __restrict__ out4 = (f4*)out;

#pragma unroll
    for (int j = 0; j < TR; ++j) {
        const int i  = rt * TR + j;    // output row within block, 0..255
        const int rl = HALO + i;       // center row in staged window
        f4 a = (f4){0.f, 0.f, 0.f, 0.f};
#pragma unroll
        for (int k = 0; k < 9; ++k) {
            a += dlds[k * BR + i] * olds[rl + OFF[k]][c];
        }
        out4[(size_t)(r0 + i) * M4 + cb4 + c] = a;
    }
}

extern "C" void kernel_launch(void* const* d_in, const int* in_sizes, int n_in,
                              void* d_out, int out_size, void* d_ws, size_t ws_size,
                              hipStream_t stream) {
    const float* diags = (const float*)d_in[0];   // 9 * 8192 fp32
    const float* other = (const float*)d_in[1];   // 8192 * 4096 fp32
    float* out         = (float*)d_out;           // 8192 * 4096 fp32

    // grid.x = 128 column stripes -> XCD = x % 8 pins each stripe (and its row-
    // overlap reuse between y and y+1) to one XCD's L2. grid.y = 32 row bands.
    dim3 block(256, 1, 1);
    dim3 grid(M4 / CB, DIA_N / BR, 1);
    sparse_dia_kernel<<<grid, block, 0, stream>>>(diags, other, out);
}

// Round 3
// 251.017 us; speedup vs baseline: 1.1362x; 1.0388x over previous
//
#include <hip/hip_runtime.h>

// SparseDIA (9 static offsets) @ dense: out[r,c] = sum_k diags[k, r+off_k] * other[r+off_k, c]
// N=8192, M=4096, fp32.
//
// Round-2 post-mortem: LDS staging cut traffic (FETCH compulsory, conflicts 6.5%)
// but stage and compute phases serialize at the per-band barrier (16 x (7K+5K)
// cycles/CU ~= observed 254K). Fix: persistent block + LDS ring buffer so band
// t+1's global_load_lds is IN FLIGHT while band t computes from LDS.
//
// Geometry: grid = 128 col-stripes x 2 row-groups = 256 blocks = 1/CU.
// Block = 8 float4 cols x 4096 rows = 16 bands of 256 rows.
// Ring = 768 rows x 128 B = 96 KB (live 512-row window + incoming 256-row chunk;
// 768 = 3*256 so 256-aligned chunks never wrap). Diags: zero-padded per-band
// slice, double-buffered (2 x 9 KB) -> edge handling is branch-free.
// Per band: {issue stage(t+1) -> compute band t from LDS -> barrier}; the
// barrier's vmcnt drain overlaps the ~1.3K-cycle compute.
// Compute: 3-row sliding register window for offsets {-1,0,1} => 58 (not 72)
// ds_read_b128 per thread per band.

#define DIA_N 8192
#define DIA_M 4096
#define M4    (DIA_M / 4)   // 1024 float4 per row
#define CB    8             // float4 cols per block (128 B stripe)
#define BR    256           // rows per band
#define HALO  128           // max |offset|
#define RING  768           // ring rows (= 3 * BR)
#define NB    16            // bands per block
#define GROUP (BR * NB)     // 4096 rows per block

typedef float f4 __attribute__((ext_vector_type(4)));
typedef __attribute__((address_space(3))) unsigned int       lds_uint;
typedef const __attribute__((address_space(1))) unsigned int glb_uint;

__global__ __launch_bounds__(256) void sparse_dia_kernel(
    const float* __restrict__ diags,   // [9, N]
    const float* __restrict__ other,   // [N, M]
    float* __restrict__ out)           // [N, M]
{
    constexpr int OFF[9] = {-128, -64, -8, -1, 0, 1, 8, 64, 128};

    __shared__ f4    ring[RING][CB];     // 96 KB, linear rows (global_load_lds dest)
    __shared__ float dlds[2][9 * BR];    // 2 x 9 KB zero-padded diag slices

    const int tid  = threadIdx.x;
    const int gr0  = blockIdx.y * GROUP;        // first output row of this block
    const int cb4  = blockIdx.x * CB;           // first float4 column

    const int wave = tid >> 6;
    const int lane = tid & 63;
    const int lrow = lane >> 3;                 // row within an 8-row gll chunk
    const int lcol = lane & 7;                  // f4 col within stripe

    // ---- stage `nrows` ring rows starting at ring slot slot0, absolute row q0 ----
    // one global_load_lds instr = 8 rows x 128 B = 1 KB (linear LDS dest).
    auto stage_ring = [&](int slot0, int q0, int nrows) {
        const int per_wave = (nrows / 8) / 4;
#pragma unroll
        for (int s = 0; s < 16; ++s) {          // max per_wave = 16 (prologue)
            if (s >= per_wave) break;
            const int inst = wave * per_wave + s;
            int q = q0 + inst * 8 + lrow;
            q = (q < 0) ? 0 : (q >= DIA_N ? DIA_N - 1 : q);  // clamp; diag=0 kills garbage
            const float* src = other + ((size_t)q * DIA_M + (size_t)(cb4 + lcol) * 4);
            __builtin_amdgcn_global_load_lds(
                (glb_uint*)src,
                (lds_uint*)&ring[slot0 + inst * 8][0],        // wave-uniform base
                16, 0, 0);
        }
    };

    // ---- stage zero-padded diag slice for band t into dlds[buf] ----
    auto stage_diag = [&](int buf, int t) {
        const int bs = gr0 + t * BR;            // band's first output row
#pragma unroll
        for (int k = 0; k < 9; ++k) {
            const int q  = bs + tid + OFF[k];
            const int qc = (q < 0) ? 0 : (q >= DIA_N ? DIA_N - 1 : q);
            float v = diags[k * DIA_N + qc];    // branchless: always-safe load
            v = ((unsigned)q < (unsigned)DIA_N) ? v : 0.f;
            dlds[buf][k * BR + tid] = v;
        }
    };

    f4* __restrict__ out4 = (f4*)out;

    // ---- prologue: full 512-row window for band 0 + its diags ----
    stage_ring(0, gr0 - HALO, 2 * BR);
    stage_diag(0, 0);
    __syncthreads();

    const int c  = tid & 7;                     // f4 col
    const int i0 = (tid >> 3) * 8;              // first of this thread's 8 band rows

    for (int t = 0; t < NB; ++t) {
        // issue next chunk + next diags BEFORE computing (overlap with compute)
        if (t + 1 < NB) {
            const int u = 2 * BR + t * BR;      // logical offset of incoming chunk
            stage_ring(u % RING, gr0 - HALO + u, BR);
            stage_diag((t + 1) & 1, t + 1);
        }

        // ---- compute band t purely from LDS ----
        const int buf  = t & 1;
        const int base = (HALO + t * BR) % RING;   // ring slot of band row i=0
        // slot(x) for x = i+off in [-128, 383]: base+x in [0, 1023] -> one cond subtract
        auto slot = [&](int x) { int s = base + x; return (s >= RING) ? s - RING : s; };

        f4 vm = ring[slot(i0 - 1)][c];
        f4 v0 = ring[slot(i0    )][c];
        f4 vp = ring[slot(i0 + 1)][c];

#pragma unroll
        for (int j = 0; j < 8; ++j) {
            const int i = i0 + j;
            float dk[9];
#pragma unroll
            for (int k = 0; k < 9; ++k) dk[k] = dlds[buf][k * BR + i];  // broadcast b32

            f4 a = dk[4] * v0;
            a += dk[3] * vm;
            a += dk[5] * vp;
            a += dk[2] * ring[slot(i - 8)][c];
            a += dk[6] * ring[slot(i + 8)][c];
            a += dk[0] * ring[slot(i - 128)][c];
            a += dk[1] * ring[slot(i - 64)][c];
            a += dk[7] * ring[slot(i + 64)][c];
            a += dk[8] * ring[slot(i + 128)][c];

            out4[(size_t)(gr0 + t * BR + i) * M4 + cb4 + c] = a;

            vm = v0; v0 = vp;
            if (j < 7) vp = ring[slot(i + 2)][c];
        }

        // all waves done reading band t's window; stage(t+1) drains here (vmcnt
        // covered by the compute above). Next iter's reads/writes are then safe.
        __syncthreads();
    }
}

extern "C" void kernel_launch(void* const* d_in, const int* in_sizes, int n_in,
                              void* d_out, int out_size, void* d_ws, size_t ws_size,
                              hipStream_t stream) {
    const float* diags = (const float*)d_in[0];   // 9 * 8192 fp32
    const float* other = (const float*)d_in[1];   // 8192 * 4096 fp32
    float* out         = (float*)d_out;           // 8192 * 4096 fp32

    // 256 blocks = 1/CU (114 KB LDS forbids co-residency): persistent stripes.
    dim3 block(256, 1, 1);
    dim3 grid(M4 / CB, DIA_N / GROUP, 1);         // (128, 2)
    sparse_dia_kernel<<<grid, block, 0, stream>>>(diags, other, out);
}

// Round 4
// 246.241 us; speedup vs baseline: 1.1582x; 1.0194x over previous
//
#include <hip/hip_runtime.h>

// SparseDIA (9 static offsets) @ dense: out[r,c] = sum_k diags[k, r+off_k] * other[r+off_k, c]
// N=8192, M=4096, fp32.
//
// Round-3 post-mortem: ring pipeline is structurally right (FETCH compulsory,
// WRITE exact) but ran at 1 wave/SIMD (Occupancy 9.4%) -> pure latency-bound:
// band time 14K cyc vs ~3.5K LDS-port floor. Fix: same kernel, 1024 threads
// (16 waves = 4/SIMD). Traffic identical; TLP x4 hides LDS + global latency.
//
// Geometry: grid = 128 col-stripes x 2 row-groups = 256 blocks = 1/CU.
// Block = 8 float4 cols x 4096 rows = 16 bands of 256 rows; 2 rows/thread/band.
// Ring = 768 rows x 128 B = 96 KB (live 512-row window + incoming 256-row chunk,
// 256-aligned chunks never wrap). Diags: zero-padded per-band slice, double-
// buffered -> branch-free edges. Per band: {issue stage(t+1) -> compute band t
// from LDS -> barrier}; gll flight time covered by compute.

#define DIA_N   8192
#define DIA_M   4096
#define M4      (DIA_M / 4)   // 1024 float4 per row
#define CB      8             // float4 cols per block (128 B stripe)
#define BR      256           // rows per band
#define HALO    128           // max |offset|
#define RING    768           // ring rows (= 3 * BR)
#define NB      16            // bands per block
#define GROUP   (BR * NB)     // 4096 rows per block
#define THREADS 1024
#define NWAVES  (THREADS / 64)
#define RT      (BR / (THREADS / 8))   // rows per thread per band = 2

typedef float f4 __attribute__((ext_vector_type(4)));
typedef __attribute__((address_space(3))) unsigned int       lds_uint;
typedef const __attribute__((address_space(1))) unsigned int glb_uint;

__global__ __launch_bounds__(THREADS) void sparse_dia_kernel(
    const float* __restrict__ diags,   // [9, N]
    const float* __restrict__ other,   // [N, M]
    float* __restrict__ out)           // [N, M]
{
    constexpr int OFF[9] = {-128, -64, -8, -1, 0, 1, 8, 64, 128};

    __shared__ f4    ring[RING][CB];     // 96 KB, linear rows (global_load_lds dest)
    __shared__ float dlds[2][9 * BR];    // 2 x 9 KB zero-padded diag slices

    const int tid  = threadIdx.x;
    const int gr0  = blockIdx.y * GROUP;        // first output row of this block
    const int cb4  = blockIdx.x * CB;           // first float4 column

    const int wave = tid >> 6;
    const int lane = tid & 63;
    const int lrow = lane >> 3;                 // row within an 8-row gll chunk
    const int lcol = lane & 7;                  // f4 col within stripe

    // ---- stage ring rows: one gll instr = 8 rows x 128 B = 1 KB (linear dest) ----
    // ninst = per-wave instruction count (compile-time at each call site).
    auto stage_ring = [&](int slot0, int q0, int ninst) {
#pragma unroll
        for (int s = 0; s < 4; ++s) {           // max ninst = 4 (prologue)
            if (s >= ninst) break;
            const int inst = wave * ninst + s;
            int q = q0 + inst * 8 + lrow;
            q = (q < 0) ? 0 : (q >= DIA_N ? DIA_N - 1 : q);  // clamp; diag=0 kills garbage
            const float* src = other + ((size_t)q * DIA_M + (size_t)(cb4 + lcol) * 4);
            __builtin_amdgcn_global_load_lds(
                (glb_uint*)src,
                (lds_uint*)&ring[slot0 + inst * 8][0],        // wave-uniform base
                16, 0, 0);
        }
    };

    // ---- stage zero-padded diag slice for band t into dlds[buf] ----
    auto stage_diag = [&](int buf, int t) {
        const int bs = gr0 + t * BR;            // band's first output row
#pragma unroll
        for (int f = tid; f < 9 * BR; f += THREADS) {
            const int k = f >> 8;               // BR = 256
            const int i = f & (BR - 1);
            const int q  = bs + i + OFF[k];
            const int qc = (q < 0) ? 0 : (q >= DIA_N ? DIA_N - 1 : q);
            float v = diags[k * DIA_N + qc];    // branchless: always-safe load
            v = ((unsigned)q < (unsigned)DIA_N) ? v : 0.f;
            dlds[buf][f] = v;
        }
    };

    f4* __restrict__ out4 = (f4*)out;

    // ---- prologue: full 512-row window for band 0 + its diags ----
    stage_ring(0, gr0 - HALO, (2 * BR / 8) / NWAVES);   // 4 instr/wave
    stage_diag(0, 0);
    __syncthreads();

    const int c  = tid & 7;                     // f4 col
    const int i0 = (tid >> 3) * RT;             // first of this thread's RT band rows

    for (int t = 0; t < NB; ++t) {
        // issue next chunk + next diags BEFORE computing (overlap with compute)
        if (t + 1 < NB) {
            const int u = 2 * BR + t * BR;      // logical offset of incoming chunk
            stage_ring(u % RING, gr0 - HALO + u, (BR / 8) / NWAVES);  // 2 instr/wave
            stage_diag((t + 1) & 1, t + 1);
        }

        // ---- compute band t purely from LDS ----
        const int buf  = t & 1;
        const int base = (HALO + t * BR) % RING;   // ring slot of band row i=0
        auto slot = [&](int x) { int s = base + x; return (s >= RING) ? s - RING : s; };

        f4 vm = ring[slot(i0 - 1)][c];
        f4 v0 = ring[slot(i0    )][c];
        f4 vp = ring[slot(i0 + 1)][c];

#pragma unroll
        for (int j = 0; j < RT; ++j) {
            const int i = i0 + j;
            float dk[9];
#pragma unroll
            for (int k = 0; k < 9; ++k) dk[k] = dlds[buf][k * BR + i];  // 8-lane broadcast

            f4 a = dk[4] * v0;
            a += dk[3] * vm;
            a += dk[5] * vp;
            a += dk[2] * ring[slot(i - 8)][c];
            a += dk[6] * ring[slot(i + 8)][c];
            a += dk[0] * ring[slot(i - 128)][c];
            a += dk[1] * ring[slot(i - 64)][c];
            a += dk[7] * ring[slot(i + 64)][c];
            a += dk[8] * ring[slot(i + 128)][c];

            out4[(size_t)(gr0 + t * BR + i) * M4 + cb4 + c] = a;

            vm = v0; v0 = vp;
            if (j < RT - 1) vp = ring[slot(i + 2)][c];
        }

        // all waves done reading band t's window; stage(t+1) gll also drains here
        // (its flight time was covered by the compute above).
        __syncthreads();
    }
}

extern "C" void kernel_launch(void* const* d_in, const int* in_sizes, int n_in,
                              void* d_out, int out_size, void* d_ws, size_t ws_size,
                              hipStream_t stream) {
    const float* diags = (const float*)d_in[0];   // 9 * 8192 fp32
    const float* other = (const float*)d_in[1];   // 8192 * 4096 fp32
    float* out         = (float*)d_out;           // 8192 * 4096 fp32

    // 256 blocks = 1/CU (114 KB LDS), 16 waves each = 4 waves/SIMD.
    dim3 block(THREADS, 1, 1);
    dim3 grid(M4 / CB, DIA_N / GROUP, 1);         // (128, 2)
    sparse_dia_kernel<<<grid, block, 0, stream>>>(diags, other, out);
}

// Round 5
// 244.429 us; speedup vs baseline: 1.1668x; 1.0074x over previous
//
#include <hip/hip_runtime.h>

// SparseDIA (9 static offsets) @ dense: out[r,c] = sum_k diags[k, r+off_k] * other[r+off_k, c]
// N=8192, M=4096, fp32.
//
// Round-4 post-mortem: single block/CU + per-band full-drain barrier leaves every
// pipe <50% busy (band = 13.6K cyc vs 6.5K LDS floor; VALUBusy 15%, conflicts 4.2M).
// Round-5 levers: (1) TWO independent blocks per CU (BR=128, RING=512 rows = 64 KB,
// 73 KB LDS/block -> 146 KB/CU) so one block computes while the other drains its
// barrier; (2) 32 waves/CU total; (3) both-sides XOR bank swizzle: ring rows all
// start at bank 0, so same-column lanes collided 8-way -- store global col
// (lcol^lrow) at LDS col lcol via pre-swizzled GLOBAL source (gll dest stays
// linear, per Guideline 21), read ring[slot][c ^ (slot&7)].
//
// Geometry: grid = 128 col-stripes x 4 row-groups = 512 blocks (2/CU).
// Block = 8 float4 cols x 2048 rows = 16 bands of 128 rows, 1 row/thread/band.
// RING = 512 = live window (BR+2*HALO=384) + incoming chunk (128); power of 2 ->
// slot arithmetic is a single AND; BR-aligned chunks never wrap.
// Diags: zero-padded per-band slice, double-buffered -> branch-free edges.

#define DIA_N   8192
#define DIA_M   4096
#define M4      (DIA_M / 4)   // 1024 float4 per row
#define CB      8             // float4 cols per block (128 B stripe)
#define BR      128           // rows per band
#define HALO    128           // max |offset|
#define RING    512           // ring rows = 2*BR + 2*HALO (power of 2)
#define NB      16            // bands per block
#define GROUP   (BR * NB)     // 2048 rows per block
#define THREADS 1024
#define NWAVES  (THREADS / 64)

typedef float f4 __attribute__((ext_vector_type(4)));
typedef __attribute__((address_space(3))) unsigned int       lds_uint;
typedef const __attribute__((address_space(1))) unsigned int glb_uint;

__global__ __launch_bounds__(THREADS, 8) void sparse_dia_kernel(
    const float* __restrict__ diags,   // [9, N]
    const float* __restrict__ other,   // [N, M]
    float* __restrict__ out)           // [N, M]
{
    constexpr int OFF[9] = {-128, -64, -8, -1, 0, 1, 8, 64, 128};

    __shared__ f4    ring[RING][CB];     // 64 KB, rows linear (gll dest), cols XOR-swizzled
    __shared__ float dlds[2][9 * BR];    // 2 x 4.5 KB zero-padded diag slices

    const int tid  = threadIdx.x;
    const int gr0  = blockIdx.y * GROUP;        // first output row of this block
    const int cb4  = blockIdx.x * CB;           // first float4 column

    const int wave = tid >> 6;
    const int lane = tid & 63;
    const int lrow = lane >> 3;                 // 0..7: row within an 8-row gll chunk
    const int lcol = lane & 7;                  // 0..7: LDS col slot this lane fills
    // Both-sides swizzle: LDS position (row, lcol) must hold global col lcol^(row&7).
    // Chunk base rows are always ==0 mod 8, so row&7 == lrow.
    const int scol = lcol ^ lrow;               // pre-swizzled GLOBAL source column

    // ---- stage ring rows: one gll instr = 8 rows x 128 B = 1 KB (linear dest) ----
    auto stage_ring = [&](int slot0, int q0, int ninst) {
#pragma unroll
        for (int s = 0; s < 3; ++s) {           // max ninst = 3 (prologue)
            if (s >= ninst) break;
            const int inst = wave * ninst + s;
            int q = q0 + inst * 8 + lrow;
            q = (q < 0) ? 0 : (q >= DIA_N ? DIA_N - 1 : q);  // clamp; diag=0 kills garbage
            const float* src = other + ((size_t)q * DIA_M + (size_t)(cb4 + scol) * 4);
            __builtin_amdgcn_global_load_lds(
                (glb_uint*)src,
                (lds_uint*)&ring[slot0 + inst * 8][0],        // wave-uniform base
                16, 0, 0);
        }
    };

    // ---- stage zero-padded diag slice for band t into dlds[buf] ----
    auto stage_diag = [&](int buf, int t) {
        const int bs = gr0 + t * BR;            // band's first output row
        for (int f = tid; f < 9 * BR; f += THREADS) {
            const int k  = f >> 7;              // BR = 128
            const int i  = f & (BR - 1);
            const int q  = bs + i + OFF[k];
            const int qc = (q < 0) ? 0 : (q >= DIA_N ? DIA_N - 1 : q);
            float v = diags[k * DIA_N + qc];    // branchless: always-safe load
            v = ((unsigned)q < (unsigned)DIA_N) ? v : 0.f;
            dlds[buf][f] = v;
        }
    };

    f4* __restrict__ out4 = (f4*)out;

    // ---- prologue: band-0 live window = logical rows [0, 384) = 48 gll instrs ----
    stage_ring(0, gr0 - HALO, 3);
    stage_diag(0, 0);
    __syncthreads();

    const int c = tid & 7;                      // f4 col
    const int i = tid >> 3;                     // band row, 0..127 (1 row/thread)

    for (int t = 0; t < NB; ++t) {
        // issue next chunk + next diags BEFORE computing (overlap with compute).
        // New logical rows for band t+1: [384 + t*BR, 512 + t*BR) -- disjoint
        // (mod RING) from band t's live window [t*BR, t*BR + 384).
        if (t + 1 < NB) {
            const int u = (BR + 2 * HALO) + t * BR;
            stage_ring(u & (RING - 1), gr0 - HALO + u, 1);
            stage_diag((t + 1) & 1, t + 1);
        }

        // ---- compute band t purely from LDS ----
        const int buf  = t & 1;
        const int base = (HALO + t * BR) & (RING - 1);  // ring slot of band row 0

        float dk[9];
#pragma unroll
        for (int k = 0; k < 9; ++k) dk[k] = dlds[buf][k * BR + i];  // 8-lane broadcast

        f4 a = (f4){0.f, 0.f, 0.f, 0.f};
#pragma unroll
        for (int k = 0; k < 9; ++k) {
            const int slot = (base + i + OFF[k]) & (RING - 1);
            a += dk[k] * ring[slot][c ^ (slot & 7)];    // swizzled read
        }

        out4[(size_t)(gr0 + t * BR + i) * M4 + cb4 + c] = a;

        // Band t reads done before t+2's prefetch overwrites them (next iter);
        // band t+1's gll data drained (vmcnt(0)) before its compute. While this
        // block sits in the drain, the CU's OTHER block computes.
        __syncthreads();
    }
}

extern "C" void kernel_launch(void* const* d_in, const int* in_sizes, int n_in,
                              void* d_out, int out_size, void* d_ws, size_t ws_size,
                              hipStream_t stream) {
    const float* diags = (const float*)d_in[0];   // 9 * 8192 fp32
    const float* other = (const float*)d_in[1];   // 8192 * 4096 fp32
    float* out         = (float*)d_out;           // 8192 * 4096 fp32

    // 512 blocks = 2/CU (73 KB LDS each), 16 waves each -> 32 waves/CU.
    dim3 block(THREADS, 1, 1);
    dim3 grid(M4 / CB, DIA_N / GROUP, 1);         // (128, 4)
    sparse_dia_kernel<<<grid, block, 0, stream>>>(diags, other, out);
}